// Round 2
// baseline (119.714 us; speedup 1.0000x reference)
//
#include <hip/hip_runtime.h>
#include <math.h>

// out[b,o] = min_i(W[o,i]+X[b,i]) + max_i(W[o,i]+X[b,i])
// B=1024, OUT=1024, IN=512, fp32. Compute-bound VALU kernel (no fp32 MFMA).
//
// R2: 512-thread blocks, split-K within block (waves 0-3: k<256, waves 4-7:
// k>=256) -> 8 waves/CU = 2 waves/SIMD so LDS-wait overlaps VALU.
// Partial min/max combined through LDS in the epilogue.

constexpr int B_DIM  = 1024;
constexpr int O_DIM  = 1024;
constexpr int IN_DIM = 512;

constexpr int BM = 64;            // batch-tile
constexpr int BN = 64;            // out-tile
constexpr int BK = 32;            // k-tile
constexpr int KHALF = IN_DIM / 2; // 256 k per half
constexpr int NT_H  = KHALF / BK; // 8 k-tiles per half

// Byte offset into one LDS tile (k-major: row k holds 64 floats = 256 B).
// XOR swizzle spreads transposed staging writes across banks (8-way -> 2-way
// = free); reads use the identical formula so 16B fragments stay contiguous.
__device__ __forceinline__ int swz(int k, int byteInRow) {
    return k * 256 + (byteInRow ^ (((k >> 2) & 7) << 4));
}

__global__ __launch_bounds__(512) void tropical_gemm(
    const float* __restrict__ X, const float* __restrict__ W,
    float* __restrict__ out) {
    // [half][buf][0=X,1=W][BK*BM floats] -> 64 KB
    __shared__ float lds[2][2][2][BK * BM];

    const int tid  = threadIdx.x;
    const int half = tid >> 8;    // k-half (0/1)
    const int htid = tid & 255;   // id within half
    const int tn   = htid & 15;   // out-dir   (0..15)
    const int tm   = htid >> 4;   // batch-dir (0..15)
    const int b0   = blockIdx.y * BM;
    const int o0   = blockIdx.x * BN;

    // staging: 8 k-chunks of 4 floats x 32 rows, two row-passes
    const int kk  = htid & 7;
    const int row = htid >> 3;

    const float* Xp = X + (size_t)(b0 + row) * IN_DIM + half * KHALF + kk * 4;
    const float* Wp = W + (size_t)(o0 + row) * IN_DIM + half * KHALF + kk * 4;

    float mn[4][4], mx[4][4];
#pragma unroll
    for (int i = 0; i < 4; ++i)
#pragma unroll
        for (int j = 0; j < 4; ++j) { mn[i][j] = INFINITY; mx[i][j] = -INFINITY; }

    // ---- prefetch + stage tile 0 of this half ----
    float4 xg0 = *(const float4*)(Xp);
    float4 xg1 = *(const float4*)(Xp + 32 * IN_DIM);
    float4 wg0 = *(const float4*)(Wp);
    float4 wg1 = *(const float4*)(Wp + 32 * IN_DIM);
    Xp += BK; Wp += BK;
    {
        char* Xd = (char*)&lds[half][0][0][0];
        char* Wd = (char*)&lds[half][0][1][0];
#pragma unroll
        for (int j = 0; j < 4; ++j) {
            *(float*)(Xd + swz(kk * 4 + j, row * 4))        = ((const float*)&xg0)[j];
            *(float*)(Xd + swz(kk * 4 + j, (row + 32) * 4)) = ((const float*)&xg1)[j];
            *(float*)(Wd + swz(kk * 4 + j, row * 4))        = ((const float*)&wg0)[j];
            *(float*)(Wd + swz(kk * 4 + j, (row + 32) * 4)) = ((const float*)&wg1)[j];
        }
    }
    __syncthreads();

    int cur = 0;
    for (int t = 0; t < NT_H; ++t) {
        const bool has_next = (t + 1 < NT_H);
        if (has_next) {  // issue next tile's global loads early
            xg0 = *(const float4*)(Xp);
            xg1 = *(const float4*)(Xp + 32 * IN_DIM);
            wg0 = *(const float4*)(Wp);
            wg1 = *(const float4*)(Wp + 32 * IN_DIM);
            Xp += BK; Wp += BK;
        }

        const char* Xs = (const char*)&lds[half][cur][0][0];
        const char* Ws = (const char*)&lds[half][cur][1][0];
#pragma unroll
        for (int k = 0; k < BK; k += 2) {
            float4 x0 = *(const float4*)(Xs + swz(k,     tm * 16));
            float4 w0 = *(const float4*)(Ws + swz(k,     tn * 16));
            float4 x1 = *(const float4*)(Xs + swz(k + 1, tm * 16));
            float4 w1 = *(const float4*)(Ws + swz(k + 1, tn * 16));
            const float xs0[4] = {x0.x, x0.y, x0.z, x0.w};
            const float ws0[4] = {w0.x, w0.y, w0.z, w0.w};
            const float xs1[4] = {x1.x, x1.y, x1.z, x1.w};
            const float ws1[4] = {w1.x, w1.y, w1.z, w1.w};
#pragma unroll
            for (int i = 0; i < 4; ++i)
#pragma unroll
                for (int j = 0; j < 4; ++j) {
                    float s0 = xs0[i] + ws0[j];
                    float s1 = xs1[i] + ws1[j];
                    // nested fminf/fmaxf -> v_min3_f32 / v_max3_f32
                    mn[i][j] = fminf(fminf(s0, s1), mn[i][j]);
                    mx[i][j] = fmaxf(fmaxf(s0, s1), mx[i][j]);
                }
        }

        if (has_next) {  // stage next tile into the other buffer
            char* Xd = (char*)&lds[half][cur ^ 1][0][0];
            char* Wd = (char*)&lds[half][cur ^ 1][1][0];
#pragma unroll
            for (int j = 0; j < 4; ++j) {
                *(float*)(Xd + swz(kk * 4 + j, row * 4))        = ((const float*)&xg0)[j];
                *(float*)(Xd + swz(kk * 4 + j, (row + 32) * 4)) = ((const float*)&xg1)[j];
                *(float*)(Wd + swz(kk * 4 + j, row * 4))        = ((const float*)&wg0)[j];
                *(float*)(Wd + swz(kk * 4 + j, (row + 32) * 4)) = ((const float*)&wg1)[j];
            }
            __syncthreads();
            cur ^= 1;
        }
    }

    // ---- combine halves through LDS, then store ----
    __syncthreads();                 // all compute done; safe to overlay LDS
    float* ex = (float*)lds;         // 256 threads x 32 floats = 32 KB overlay
    if (half == 1) {
        float* p = ex + htid * 32;
#pragma unroll
        for (int i = 0; i < 4; ++i) {
            *(float4*)(p + i * 4)      = make_float4(mn[i][0], mn[i][1], mn[i][2], mn[i][3]);
            *(float4*)(p + 16 + i * 4) = make_float4(mx[i][0], mx[i][1], mx[i][2], mx[i][3]);
        }
    }
    __syncthreads();
    if (half == 0) {
        const float* p = ex + htid * 32;
        float* op = out + (size_t)(b0 + tm * 4) * O_DIM + o0 + tn * 4;
#pragma unroll
        for (int i = 0; i < 4; ++i) {
            float4 pmn = *(const float4*)(p + i * 4);
            float4 pmx = *(const float4*)(p + 16 + i * 4);
            float4 r;
            r.x = fminf(mn[i][0], pmn.x) + fmaxf(mx[i][0], pmx.x);
            r.y = fminf(mn[i][1], pmn.y) + fmaxf(mx[i][1], pmx.y);
            r.z = fminf(mn[i][2], pmn.z) + fmaxf(mx[i][2], pmx.z);
            r.w = fminf(mn[i][3], pmn.w) + fmaxf(mx[i][3], pmx.w);
            *(float4*)(op + (size_t)i * O_DIM) = r;
        }
    }
}

extern "C" void kernel_launch(void* const* d_in, const int* in_sizes, int n_in,
                              void* d_out, int out_size, void* d_ws, size_t ws_size,
                              hipStream_t stream) {
    (void)in_sizes; (void)n_in; (void)d_ws; (void)ws_size; (void)out_size;
    const float* X = (const float*)d_in[0];
    const float* W = (const float*)d_in[1];
    float* out     = (float*)d_out;

    dim3 grid(O_DIM / BN, B_DIM / BM);  // (16, 16) = 256 blocks = 1/CU
    tropical_gemm<<<grid, dim3(512), 0, stream>>>(X, W, out);
}

// Round 3
// 70.130 us; speedup vs baseline: 1.7070x; 1.7070x over previous
//
#include <hip/hip_runtime.h>
#include <math.h>

// out[b,o] = min_i(W[o,i]+X[b,i]) + max_i(W[o,i]+X[b,i])
// B=1024, OUT=1024, IN=512, fp32.
//
// R3 design: 64x64 output tile per 512-thread block (256 blocks = 1/CU).
// 8 waves per block, each wave owns a PRIVATE k-slice of 64 (split-K in
// block) and an 8x8 per-lane micro-tile -> halves LDS instr count vs 4x4
// and removes ALL main-loop barriers (wave-private LDS double buffers).
// 2 waves/SIMD occupancy. Partial min/max merged via 3-round LDS tree.

constexpr int B_DIM  = 1024;
constexpr int O_DIM  = 1024;
constexpr int IN_DIM = 512;

constexpr int TILE   = 64;  // output tile (both dims)
constexpr int KW     = 64;  // k-range per wave (512 / 8 waves)
constexpr int BK     = 8;   // k per stage
constexpr int NSTAGE = KW / BK;  // 8 stages

// LDS: [wave][buf][op][k][64 floats] = 8*2*2*8*64 floats = 64 KB.
// Reused as merge dump area (4 slots x 4096 floats) in the epilogue.
constexpr int WAVE_LDS = 2 * 2 * BK * 64;  // floats per wave region

__global__ __launch_bounds__(512, 2) void tropical_gemm(
    const float* __restrict__ X, const float* __restrict__ W,
    float* __restrict__ out) {
    __shared__ float lds[8 * WAVE_LDS];

    const int tid  = threadIdx.x;
    const int w    = tid >> 6;
    const int lane = tid & 63;
    const int im   = lane >> 3;  // row-block 0..7
    const int in_  = lane & 7;   // col-block 0..7
    const int b0   = blockIdx.y * TILE;
    const int o0   = blockIdx.x * TILE;

    const float* Xp = X + (size_t)(b0 + lane) * IN_DIM + w * KW;
    const float* Wp = W + (size_t)(o0 + lane) * IN_DIM + w * KW;

    float* wbase = &lds[w * WAVE_LDS];  // this wave's private region

    float mn[8][8], mx[8][8];
#pragma unroll
    for (int i = 0; i < 8; ++i)
#pragma unroll
        for (int j = 0; j < 8; ++j) { mn[i][j] = INFINITY; mx[i][j] = -INFINITY; }

    // ---- prologue: load + stage k-chunk 0 into buf 0 ----
    float4 xa = *(const float4*)(Xp);
    float4 xb = *(const float4*)(Xp + 4);
    float4 wa = *(const float4*)(Wp);
    float4 wb = *(const float4*)(Wp + 4);
    {
        float* dX = wbase;        // buf 0, op X: [k][64]
        float* dW = wbase + BK * 64;
#pragma unroll
        for (int j = 0; j < 4; ++j) {
            dX[j * 64 + lane]       = ((const float*)&xa)[j];
            dX[(4 + j) * 64 + lane] = ((const float*)&xb)[j];
            dW[j * 64 + lane]       = ((const float*)&wa)[j];
            dW[(4 + j) * 64 + lane] = ((const float*)&wb)[j];
        }
    }

    for (int s = 0; s < NSTAGE; ++s) {
        const bool has_next = (s + 1 < NSTAGE);
        if (has_next) {  // issue next chunk's global loads; latency hides under compute
            xa = *(const float4*)(Xp + (s + 1) * BK);
            xb = *(const float4*)(Xp + (s + 1) * BK + 4);
            wa = *(const float4*)(Wp + (s + 1) * BK);
            wb = *(const float4*)(Wp + (s + 1) * BK + 4);
        }

        const float* sX = wbase + (s & 1) * (2 * BK * 64);
        const float* sW = sX + BK * 64;
#pragma unroll
        for (int k = 0; k < BK; k += 2) {
            float4 x0a = *(const float4*)(sX + k * 64 + im * 8);
            float4 x0b = *(const float4*)(sX + k * 64 + im * 8 + 4);
            float4 x1a = *(const float4*)(sX + (k + 1) * 64 + im * 8);
            float4 x1b = *(const float4*)(sX + (k + 1) * 64 + im * 8 + 4);
            float4 w0a = *(const float4*)(sW + k * 64 + in_ * 8);
            float4 w0b = *(const float4*)(sW + k * 64 + in_ * 8 + 4);
            float4 w1a = *(const float4*)(sW + (k + 1) * 64 + in_ * 8);
            float4 w1b = *(const float4*)(sW + (k + 1) * 64 + in_ * 8 + 4);
            const float xs0[8] = {x0a.x, x0a.y, x0a.z, x0a.w, x0b.x, x0b.y, x0b.z, x0b.w};
            const float xs1[8] = {x1a.x, x1a.y, x1a.z, x1a.w, x1b.x, x1b.y, x1b.z, x1b.w};
            const float ws0[8] = {w0a.x, w0a.y, w0a.z, w0a.w, w0b.x, w0b.y, w0b.z, w0b.w};
            const float ws1[8] = {w1a.x, w1a.y, w1a.z, w1a.w, w1b.x, w1b.y, w1b.z, w1b.w};
#pragma unroll
            for (int a = 0; a < 8; ++a)
#pragma unroll
                for (int b = 0; b < 8; ++b) {
                    float s0 = xs0[a] + ws0[b];
                    float s1 = xs1[a] + ws1[b];
                    mn[a][b] = fminf(fminf(s0, s1), mn[a][b]);  // -> v_min3_f32
                    mx[a][b] = fmaxf(fmaxf(s0, s1), mx[a][b]);  // -> v_max3_f32
                }
        }

        if (has_next) {  // stage next chunk into the other private buffer
            float* dX = wbase + ((s + 1) & 1) * (2 * BK * 64);
            float* dW = dX + BK * 64;
#pragma unroll
            for (int j = 0; j < 4; ++j) {
                dX[j * 64 + lane]       = ((const float*)&xa)[j];
                dX[(4 + j) * 64 + lane] = ((const float*)&xb)[j];
                dW[j * 64 + lane]       = ((const float*)&wa)[j];
                dW[(4 + j) * 64 + lane] = ((const float*)&wb)[j];
            }
        }
    }

    // ---- merge 8 wave-partials via LDS tree (reuse tile LDS as dump) ----
    // dump slot layout: [slot][j][lane][4]  (j = r*2 + c4), 4096 floats/slot
    float* dump = lds;

    auto dumpA = [&](float (&a)[8][8], int slot) {
        float* p = dump + slot * 4096 + lane * 4;
#pragma unroll
        for (int r = 0; r < 8; ++r)
#pragma unroll
            for (int c4 = 0; c4 < 2; ++c4)
                *(float4*)(p + (r * 2 + c4) * 256) =
                    make_float4(a[r][c4 * 4 + 0], a[r][c4 * 4 + 1],
                                a[r][c4 * 4 + 2], a[r][c4 * 4 + 3]);
    };
    auto mergeMin = [&](float (&a)[8][8], int slot) {
        const float* p = dump + slot * 4096 + lane * 4;
#pragma unroll
        for (int r = 0; r < 8; ++r)
#pragma unroll
            for (int c4 = 0; c4 < 2; ++c4) {
                float4 v = *(const float4*)(p + (r * 2 + c4) * 256);
                a[r][c4 * 4 + 0] = fminf(a[r][c4 * 4 + 0], v.x);
                a[r][c4 * 4 + 1] = fminf(a[r][c4 * 4 + 1], v.y);
                a[r][c4 * 4 + 2] = fminf(a[r][c4 * 4 + 2], v.z);
                a[r][c4 * 4 + 3] = fminf(a[r][c4 * 4 + 3], v.w);
            }
    };
    auto mergeMax = [&](float (&a)[8][8], int slot) {
        const float* p = dump + slot * 4096 + lane * 4;
#pragma unroll
        for (int r = 0; r < 8; ++r)
#pragma unroll
            for (int c4 = 0; c4 < 2; ++c4) {
                float4 v = *(const float4*)(p + (r * 2 + c4) * 256);
                a[r][c4 * 4 + 0] = fmaxf(a[r][c4 * 4 + 0], v.x);
                a[r][c4 * 4 + 1] = fmaxf(a[r][c4 * 4 + 1], v.y);
                a[r][c4 * 4 + 2] = fmaxf(a[r][c4 * 4 + 2], v.z);
                a[r][c4 * 4 + 3] = fmaxf(a[r][c4 * 4 + 3], v.w);
            }
    };

    __syncthreads();                       // main-loop LDS use complete
    // Round 1: 8 -> 4   (waves 4..7 -> slots 0..3), mn then mx phases
    if (w >= 4) dumpA(mn, w - 4);
    __syncthreads();
    if (w < 4) mergeMin(mn, w);
    __syncthreads();
    if (w >= 4) dumpA(mx, w - 4);
    __syncthreads();
    if (w < 4) mergeMax(mx, w);
    __syncthreads();
    // Round 2: 4 -> 2   (waves 2,3 dump both arrays)
    if (w == 2 || w == 3) { dumpA(mn, (w - 2) * 2); dumpA(mx, (w - 2) * 2 + 1); }
    __syncthreads();
    if (w < 2) { mergeMin(mn, w * 2); mergeMax(mx, w * 2 + 1); }
    __syncthreads();
    // Round 3: 2 -> 1
    if (w == 1) { dumpA(mn, 0); dumpA(mx, 1); }
    __syncthreads();
    if (w == 0) {
        mergeMin(mn, 0); mergeMax(mx, 1);
        float* op = out + (size_t)(b0 + im * 8) * O_DIM + o0 + in_ * 8;
#pragma unroll
        for (int r = 0; r < 8; ++r)
#pragma unroll
            for (int c4 = 0; c4 < 2; ++c4) {
                float4 v = make_float4(mn[r][c4 * 4 + 0] + mx[r][c4 * 4 + 0],
                                       mn[r][c4 * 4 + 1] + mx[r][c4 * 4 + 1],
                                       mn[r][c4 * 4 + 2] + mx[r][c4 * 4 + 2],
                                       mn[r][c4 * 4 + 3] + mx[r][c4 * 4 + 3]);
                *(float4*)(op + (size_t)r * O_DIM + c4 * 4) = v;
            }
    }
}

extern "C" void kernel_launch(void* const* d_in, const int* in_sizes, int n_in,
                              void* d_out, int out_size, void* d_ws, size_t ws_size,
                              hipStream_t stream) {
    (void)in_sizes; (void)n_in; (void)d_ws; (void)ws_size; (void)out_size;
    const float* X = (const float*)d_in[0];
    const float* W = (const float*)d_in[1];
    float* out     = (float*)d_out;

    dim3 grid(O_DIM / TILE, B_DIM / TILE);  // (16, 16) = 256 blocks
    tropical_gemm<<<grid, dim3(512), 0, stream>>>(X, W, out);
}

// Round 4
// 45.565 us; speedup vs baseline: 2.6274x; 1.5391x over previous
//
#include <hip/hip_runtime.h>
#include <math.h>

// out[b,o] = min_i(W[o,i]+X[b,i]) + max_i(W[o,i]+X[b,i])
// B=1024, OUT=1024, IN=512, fp32.
//
// R4: 256-thread blocks (4 waves), 64x64 tile, grid 16x16=256 (1 block/CU).
// Each wave: PRIVATE k-slice of 128, full 64x64 tile, 8x8 per-lane micro
// (64 lanes x 64 elems). Wave-private double-buffered LDS (8 KB/wave, BK=8)
// -> zero barriers in main loop. 2-round LDS merge tree via macros (no
// lambdas / no address-taken arrays -> accumulators stay in VGPRs).

constexpr int B_DIM  = 1024;
constexpr int O_DIM  = 1024;
constexpr int IN_DIM = 512;

constexpr int TILE   = 64;
constexpr int KW     = 128;          // k per wave (512 / 4 waves)
constexpr int BK     = 8;            // k per stage
constexpr int NSTAGE = KW / BK;      // 16

// Per-wave LDS: [buf2][op2][k8][64 rows] = 2048 floats = 8 KB. 4 waves = 32 KB.
// Epilogue overlays 2 dump slots x 8192 floats (32 KB each) -> 64 KB total.
__global__ __launch_bounds__(256) void tropical_gemm(
    const float* __restrict__ X, const float* __restrict__ W,
    float* __restrict__ out) {
    __shared__ float lds[16384];   // 64 KB

    const int tid  = threadIdx.x;
    const int w    = tid >> 6;     // wave 0..3
    const int lane = tid & 63;
    const int im   = lane >> 3;    // micro-row block 0..7
    const int in_  = lane & 7;     // micro-col block 0..7
    const int b0   = blockIdx.y * TILE;
    const int o0   = blockIdx.x * TILE;

    const float* Xp = X + (size_t)(b0 + lane) * IN_DIM + w * KW;
    const float* Wp = W + (size_t)(o0 + lane) * IN_DIM + w * KW;

    float* wbase = &lds[w * 2048];  // wave-private region

    float mn[8][8], mx[8][8];
#pragma unroll
    for (int i = 0; i < 8; ++i)
#pragma unroll
        for (int j = 0; j < 8; ++j) { mn[i][j] = INFINITY; mx[i][j] = -INFINITY; }

    // stage chunk into buf: layout buf*1024 + op*512 + k*64 + row
#define STAGE(bufsel)                                                         \
    do {                                                                      \
        float* d_ = wbase + (bufsel) * 1024;                                  \
        _Pragma("unroll")                                                     \
        for (int j_ = 0; j_ < 4; ++j_) {                                      \
            d_[j_ * 64 + lane]         = ((const float*)&xa)[j_];             \
            d_[(4 + j_) * 64 + lane]   = ((const float*)&xb)[j_];             \
            d_[512 + j_ * 64 + lane]   = ((const float*)&wa)[j_];             \
            d_[512 + (4 + j_) * 64 + lane] = ((const float*)&wb)[j_];         \
        }                                                                     \
    } while (0)

    // ---- prologue: load + stage stage-0 ----
    float4 xa = *(const float4*)(Xp);
    float4 xb = *(const float4*)(Xp + 4);
    float4 wa = *(const float4*)(Wp);
    float4 wb = *(const float4*)(Wp + 4);
    STAGE(0);

#pragma unroll 1
    for (int s = 0; s < NSTAGE; ++s) {
        if (s + 1 < NSTAGE) {  // prefetch next chunk (consumed at loop bottom)
            xa = *(const float4*)(Xp + (s + 1) * BK);
            xb = *(const float4*)(Xp + (s + 1) * BK + 4);
            wa = *(const float4*)(Wp + (s + 1) * BK);
            wb = *(const float4*)(Wp + (s + 1) * BK + 4);
        }

        const float* sX = wbase + (s & 1) * 1024;
        const float* sW = sX + 512;
#pragma unroll
        for (int k = 0; k < BK; k += 2) {
            float4 x0a = *(const float4*)(sX + k * 64 + im * 8);
            float4 x0b = *(const float4*)(sX + k * 64 + im * 8 + 4);
            float4 x1a = *(const float4*)(sX + (k + 1) * 64 + im * 8);
            float4 x1b = *(const float4*)(sX + (k + 1) * 64 + im * 8 + 4);
            float4 w0a = *(const float4*)(sW + k * 64 + in_ * 8);
            float4 w0b = *(const float4*)(sW + k * 64 + in_ * 8 + 4);
            float4 w1a = *(const float4*)(sW + (k + 1) * 64 + in_ * 8);
            float4 w1b = *(const float4*)(sW + (k + 1) * 64 + in_ * 8 + 4);
            const float xs0[8] = {x0a.x, x0a.y, x0a.z, x0a.w, x0b.x, x0b.y, x0b.z, x0b.w};
            const float xs1[8] = {x1a.x, x1a.y, x1a.z, x1a.w, x1b.x, x1b.y, x1b.z, x1b.w};
            const float ws0[8] = {w0a.x, w0a.y, w0a.z, w0a.w, w0b.x, w0b.y, w0b.z, w0b.w};
            const float ws1[8] = {w1a.x, w1a.y, w1a.z, w1a.w, w1b.x, w1b.y, w1b.z, w1b.w};
#pragma unroll
            for (int a = 0; a < 8; ++a)
#pragma unroll
                for (int b = 0; b < 8; ++b) {
                    float s0 = xs0[a] + ws0[b];
                    float s1 = xs1[a] + ws1[b];
                    mn[a][b] = fminf(fminf(s0, s1), mn[a][b]);  // v_min3_f32
                    mx[a][b] = fmaxf(fmaxf(s0, s1), mx[a][b]);  // v_max3_f32
                }
        }

        if (s + 1 < NSTAGE) STAGE((s + 1) & 1);
    }
#undef STAGE

    // ---- merge 4 wave partials: 2-round LDS tree ----
    // dump slot layout: [j32][lane][4floats]; j = r*2+c for mn (0..15), 16+ for mx
#define DUMP_STATE(slotbase)                                                  \
    do {                                                                      \
        float* p_ = (slotbase) + lane * 4;                                    \
        _Pragma("unroll")                                                     \
        for (int r_ = 0; r_ < 8; ++r_)                                        \
            _Pragma("unroll")                                                 \
            for (int c_ = 0; c_ < 2; ++c_) {                                  \
                *(float4*)(p_ + (r_ * 2 + c_) * 256) =                        \
                    make_float4(mn[r_][c_ * 4], mn[r_][c_ * 4 + 1],           \
                                mn[r_][c_ * 4 + 2], mn[r_][c_ * 4 + 3]);      \
                *(float4*)(p_ + (16 + r_ * 2 + c_) * 256) =                   \
                    make_float4(mx[r_][c_ * 4], mx[r_][c_ * 4 + 1],           \
                                mx[r_][c_ * 4 + 2], mx[r_][c_ * 4 + 3]);      \
            }                                                                 \
    } while (0)

#define MERGE_STATE(slotbase)                                                 \
    do {                                                                      \
        const float* p_ = (slotbase) + lane * 4;                              \
        _Pragma("unroll")                                                     \
        for (int r_ = 0; r_ < 8; ++r_)                                        \
            _Pragma("unroll")                                                 \
            for (int c_ = 0; c_ < 2; ++c_) {                                  \
                float4 vn_ = *(const float4*)(p_ + (r_ * 2 + c_) * 256);      \
                float4 vx_ = *(const float4*)(p_ + (16 + r_ * 2 + c_) * 256); \
                mn[r_][c_ * 4]     = fminf(mn[r_][c_ * 4],     vn_.x);        \
                mn[r_][c_ * 4 + 1] = fminf(mn[r_][c_ * 4 + 1], vn_.y);        \
                mn[r_][c_ * 4 + 2] = fminf(mn[r_][c_ * 4 + 2], vn_.z);        \
                mn[r_][c_ * 4 + 3] = fminf(mn[r_][c_ * 4 + 3], vn_.w);        \
                mx[r_][c_ * 4]     = fmaxf(mx[r_][c_ * 4],     vx_.x);        \
                mx[r_][c_ * 4 + 1] = fmaxf(mx[r_][c_ * 4 + 1], vx_.y);        \
                mx[r_][c_ * 4 + 2] = fmaxf(mx[r_][c_ * 4 + 2], vx_.z);        \
                mx[r_][c_ * 4 + 3] = fmaxf(mx[r_][c_ * 4 + 3], vx_.w);        \
            }                                                                 \
    } while (0)

    float* slotA = lds;           // 8192 floats
    float* slotB = lds + 8192;

    __syncthreads();
    if (w == 2) DUMP_STATE(slotA);
    if (w == 3) DUMP_STATE(slotB);
    __syncthreads();
    if (w == 0) MERGE_STATE(slotA);   // w0 <- {w0,w2}
    if (w == 1) MERGE_STATE(slotB);   // w1 <- {w1,w3}
    __syncthreads();
    if (w == 1) DUMP_STATE(slotA);
    __syncthreads();
    if (w == 0) {
        MERGE_STATE(slotA);           // w0 <- all
        float* op = out + (size_t)(b0 + im * 8) * O_DIM + o0 + in_ * 8;
#pragma unroll
        for (int r = 0; r < 8; ++r) {
            float4 v0 = make_float4(mn[r][0] + mx[r][0], mn[r][1] + mx[r][1],
                                    mn[r][2] + mx[r][2], mn[r][3] + mx[r][3]);
            float4 v1 = make_float4(mn[r][4] + mx[r][4], mn[r][5] + mx[r][5],
                                    mn[r][6] + mx[r][6], mn[r][7] + mx[r][7]);
            *(float4*)(op + (size_t)r * O_DIM)     = v0;
            *(float4*)(op + (size_t)r * O_DIM + 4) = v1;
        }
    }
#undef DUMP_STATE
#undef MERGE_STATE
}

extern "C" void kernel_launch(void* const* d_in, const int* in_sizes, int n_in,
                              void* d_out, int out_size, void* d_ws, size_t ws_size,
                              hipStream_t stream) {
    (void)in_sizes; (void)n_in; (void)d_ws; (void)ws_size; (void)out_size;
    const float* X = (const float*)d_in[0];
    const float* W = (const float*)d_in[1];
    float* out     = (float*)d_out;

    dim3 grid(O_DIM / TILE, B_DIM / TILE);  // 16x16 = 256 blocks
    tropical_gemm<<<grid, dim3(256), 0, stream>>>(X, W, out);
}

// Round 5
// 41.858 us; speedup vs baseline: 2.8600x; 1.0885x over previous
//
#include <hip/hip_runtime.h>
#include <math.h>

// out[b,o] = min_i(W[o,i]+X[b,i]) + max_i(W[o,i]+X[b,i])
// B=1024, OUT=1024, IN=512, fp32.
//
// R5 = R4 skeleton (256-thread blocks, 4 waves, wave-private k-slice 128,
// double-buffered 8KB/wave LDS, no main-loop barriers, macro merge tree)
// plus:
//  1. inline-asm v_min3_f32 / v_max3_f32 (R4 disasm-model says the fminf
//     chain did NOT fuse -> 6 VALU per 2 triples; asm forces 4).
//  2. explicit 1-kpair-ahead software pipeline of the 8 ds_read_b128 per
//     k-pair (A/B register sets) so LDS latency hides under compute.

typedef float f4 __attribute__((ext_vector_type(4)));

constexpr int B_DIM  = 1024;
constexpr int O_DIM  = 1024;
constexpr int IN_DIM = 512;

constexpr int TILE   = 64;
constexpr int KW     = 128;          // k per wave (512 / 4 waves)
constexpr int BK     = 8;            // k per stage
constexpr int NSTAGE = KW / BK;      // 16

__global__ __launch_bounds__(256) void tropical_gemm(
    const float* __restrict__ X, const float* __restrict__ W,
    float* __restrict__ out) {
    __shared__ float lds[16384];   // 64 KB; main loop uses first 32 KB

    const int tid  = threadIdx.x;
    const int w    = tid >> 6;     // wave 0..3
    const int lane = tid & 63;
    const int im   = lane >> 3;    // micro-row block 0..7
    const int in_  = lane & 7;     // micro-col block 0..7
    const int b0   = blockIdx.y * TILE;
    const int o0   = blockIdx.x * TILE;
    const int xoff = im * 8;
    const int woff = in_ * 8;

    const float* Xp = X + (size_t)(b0 + lane) * IN_DIM + w * KW;
    const float* Wp = W + (size_t)(o0 + lane) * IN_DIM + w * KW;

    float* wbase = &lds[w * 2048];  // wave-private region (8 KB)

    float mn[8][8], mx[8][8];
#pragma unroll
    for (int i = 0; i < 8; ++i)
#pragma unroll
        for (int j = 0; j < 8; ++j) { mn[i][j] = INFINITY; mx[i][j] = -INFINITY; }

    // stage chunk into buf: layout buf*1024 + op*512 + k*64 + row
#define STAGE(bufsel)                                                         \
    do {                                                                      \
        float* d_ = wbase + (bufsel) * 1024;                                  \
        _Pragma("unroll")                                                     \
        for (int j_ = 0; j_ < 4; ++j_) {                                      \
            d_[j_ * 64 + lane]             = xa[j_];                          \
            d_[(4 + j_) * 64 + lane]       = xb[j_];                          \
            d_[512 + j_ * 64 + lane]       = wa[j_];                          \
            d_[512 + (4 + j_) * 64 + lane] = wb[j_];                          \
        }                                                                     \
    } while (0)

    // load one k-pair's 8 quads (4 X rows x 2 k, 8 each) into register set P
#define LOADQ(P, kp)                                                          \
    do {                                                                      \
        P##x0  = *(const f4*)(sXf + (2 * (kp)) * 64 + xoff);                  \
        P##x0b = *(const f4*)(sXf + (2 * (kp)) * 64 + xoff + 4);              \
        P##x1  = *(const f4*)(sXf + (2 * (kp) + 1) * 64 + xoff);              \
        P##x1b = *(const f4*)(sXf + (2 * (kp) + 1) * 64 + xoff + 4);          \
        P##w0  = *(const f4*)(sWf + (2 * (kp)) * 64 + woff);                  \
        P##w0b = *(const f4*)(sWf + (2 * (kp)) * 64 + woff + 4);              \
        P##w1  = *(const f4*)(sWf + (2 * (kp) + 1) * 64 + woff);              \
        P##w1b = *(const f4*)(sWf + (2 * (kp) + 1) * 64 + woff + 4);          \
    } while (0)

    // 64 (a,b) pairs over 2 k's: 2 v_add + forced v_min3 + v_max3 each
#define COMPUTE(P)                                                            \
    do {                                                                      \
        _Pragma("unroll")                                                     \
        for (int a_ = 0; a_ < 8; ++a_) {                                      \
            const float x0_ = (a_ < 4) ? P##x0[a_] : P##x0b[a_ - 4];          \
            const float x1_ = (a_ < 4) ? P##x1[a_] : P##x1b[a_ - 4];          \
            _Pragma("unroll")                                                 \
            for (int b_ = 0; b_ < 8; ++b_) {                                  \
                const float w0_ = (b_ < 4) ? P##w0[b_] : P##w0b[b_ - 4];      \
                const float w1_ = (b_ < 4) ? P##w1[b_] : P##w1b[b_ - 4];      \
                float s0_ = x0_ + w0_;                                        \
                float s1_ = x1_ + w1_;                                        \
                asm("v_min3_f32 %0, %1, %2, %0"                               \
                    : "+v"(mn[a_][b_]) : "v"(s0_), "v"(s1_));                 \
                asm("v_max3_f32 %0, %1, %2, %0"                               \
                    : "+v"(mx[a_][b_]) : "v"(s0_), "v"(s1_));                 \
            }                                                                 \
        }                                                                     \
    } while (0)

    // ---- prologue: load + stage stage-0 ----
    f4 xa = *(const f4*)(Xp);
    f4 xb = *(const f4*)(Xp + 4);
    f4 wa = *(const f4*)(Wp);
    f4 wb = *(const f4*)(Wp + 4);
    STAGE(0);

#pragma unroll 1
    for (int s = 0; s < NSTAGE; ++s) {
        if (s + 1 < NSTAGE) {  // prefetch next chunk's globals (consumed at bottom)
            xa = *(const f4*)(Xp + (s + 1) * BK);
            xb = *(const f4*)(Xp + (s + 1) * BK + 4);
            wa = *(const f4*)(Wp + (s + 1) * BK);
            wb = *(const f4*)(Wp + (s + 1) * BK + 4);
        }

        const float* sXf = wbase + (s & 1) * 1024;
        const float* sWf = sXf + 512;

        f4 Ax0, Ax0b, Ax1, Ax1b, Aw0, Aw0b, Aw1, Aw1b;
        f4 Bx0, Bx0b, Bx1, Bx1b, Bw0, Bw0b, Bw1, Bw1b;

        LOADQ(A, 0);
        LOADQ(B, 1);
        COMPUTE(A);            // kp0 (kp2 not yet loaded; B=kp1 in flight)
        LOADQ(A, 2);
        COMPUTE(B);            // kp1 (A=kp2 in flight)
        LOADQ(B, 3);
        COMPUTE(A);            // kp2 (B=kp3 in flight)
        COMPUTE(B);            // kp3

        if (s + 1 < NSTAGE) STAGE((s + 1) & 1);
    }
#undef STAGE
#undef LOADQ
#undef COMPUTE

    // ---- merge 4 wave partials: 2-round LDS tree (verbatim from R4) ----
#define DUMP_STATE(slotbase)                                                  \
    do {                                                                      \
        float* p_ = (slotbase) + lane * 4;                                    \
        _Pragma("unroll")                                                     \
        for (int r_ = 0; r_ < 8; ++r_)                                        \
            _Pragma("unroll")                                                 \
            for (int c_ = 0; c_ < 2; ++c_) {                                  \
                *(float4*)(p_ + (r_ * 2 + c_) * 256) =                        \
                    make_float4(mn[r_][c_ * 4], mn[r_][c_ * 4 + 1],           \
                                mn[r_][c_ * 4 + 2], mn[r_][c_ * 4 + 3]);      \
                *(float4*)(p_ + (16 + r_ * 2 + c_) * 256) =                   \
                    make_float4(mx[r_][c_ * 4], mx[r_][c_ * 4 + 1],           \
                                mx[r_][c_ * 4 + 2], mx[r_][c_ * 4 + 3]);      \
            }                                                                 \
    } while (0)

#define MERGE_STATE(slotbase)                                                 \
    do {                                                                      \
        const float* p_ = (slotbase) + lane * 4;                              \
        _Pragma("unroll")                                                     \
        for (int r_ = 0; r_ < 8; ++r_)                                        \
            _Pragma("unroll")                                                 \
            for (int c_ = 0; c_ < 2; ++c_) {                                  \
                float4 vn_ = *(const float4*)(p_ + (r_ * 2 + c_) * 256);      \
                float4 vx_ = *(const float4*)(p_ + (16 + r_ * 2 + c_) * 256); \
                mn[r_][c_ * 4]     = fminf(mn[r_][c_ * 4],     vn_.x);        \
                mn[r_][c_ * 4 + 1] = fminf(mn[r_][c_ * 4 + 1], vn_.y);        \
                mn[r_][c_ * 4 + 2] = fminf(mn[r_][c_ * 4 + 2], vn_.z);        \
                mn[r_][c_ * 4 + 3] = fminf(mn[r_][c_ * 4 + 3], vn_.w);        \
                mx[r_][c_ * 4]     = fmaxf(mx[r_][c_ * 4],     vx_.x);        \
                mx[r_][c_ * 4 + 1] = fmaxf(mx[r_][c_ * 4 + 1], vx_.y);        \
                mx[r_][c_ * 4 + 2] = fmaxf(mx[r_][c_ * 4 + 2], vx_.z);        \
                mx[r_][c_ * 4 + 3] = fmaxf(mx[r_][c_ * 4 + 3], vx_.w);        \
            }                                                                 \
    } while (0)

    float* slotA = lds;           // 8192 floats
    float* slotB = lds + 8192;

    __syncthreads();
    if (w == 2) DUMP_STATE(slotA);
    if (w == 3) DUMP_STATE(slotB);
    __syncthreads();
    if (w == 0) MERGE_STATE(slotA);   // w0 <- {w0,w2}
    if (w == 1) MERGE_STATE(slotB);   // w1 <- {w1,w3}
    __syncthreads();
    if (w == 1) DUMP_STATE(slotA);
    __syncthreads();
    if (w == 0) {
        MERGE_STATE(slotA);           // w0 <- all
        float* op = out + (size_t)(b0 + im * 8) * O_DIM + o0 + in_ * 8;
#pragma unroll
        for (int r = 0; r < 8; ++r) {
            float4 v0 = make_float4(mn[r][0] + mx[r][0], mn[r][1] + mx[r][1],
                                    mn[r][2] + mx[r][2], mn[r][3] + mx[r][3]);
            float4 v1 = make_float4(mn[r][4] + mx[r][4], mn[r][5] + mx[r][5],
                                    mn[r][6] + mx[r][6], mn[r][7] + mx[r][7]);
            *(float4*)(op + (size_t)r * O_DIM)     = v0;
            *(float4*)(op + (size_t)r * O_DIM + 4) = v1;
        }
    }
#undef DUMP_STATE
#undef MERGE_STATE
}

extern "C" void kernel_launch(void* const* d_in, const int* in_sizes, int n_in,
                              void* d_out, int out_size, void* d_ws, size_t ws_size,
                              hipStream_t stream) {
    (void)in_sizes; (void)n_in; (void)d_ws; (void)ws_size; (void)out_size;
    const float* X = (const float*)d_in[0];
    const float* W = (const float*)d_in[1];
    float* out     = (float*)d_out;

    dim3 grid(O_DIM / TILE, B_DIM / TILE);  // 16x16 = 256 blocks
    tropical_gemm<<<grid, dim3(256), 0, stream>>>(X, W, out);
}

// Round 6
// 31.665 us; speedup vs baseline: 3.7807x; 1.3219x over previous
//
#include <hip/hip_runtime.h>
#include <math.h>

// out[b,o] = min_i(W[o,i]+X[b,i]) + max_i(W[o,i]+X[b,i])
// B=1024, OUT=1024, IN=512, fp32.
//
// R6: occupancy fix. Tile 64x32, grid 32x16 = 512 blocks = 2 blocks/CU
// -> 2 waves/SIMD (R5 post-mortem: 1 wave/SIMD left ~65% latency idle;
// VALU issue is only ~13.6us, LDS pipe ~19us at this micro-shape).
// Block: 256 threads / 4 waves; each wave owns PRIVATE k-slice of 128 and
// the whole 64x32 tile with an 8x4 per-lane micro (64 accum VGPRs).
// Wave-private double-buffered LDS (6KB/wave), zero main-loop barriers,
// asm v_min3/v_max3, A/B k-pair pipeline, macro merge tree (2 rounds).

typedef float f4 __attribute__((ext_vector_type(4)));

constexpr int B_DIM  = 1024;
constexpr int O_DIM  = 1024;
constexpr int IN_DIM = 512;

constexpr int TM     = 64;           // batch-tile
constexpr int TN     = 32;           // out-tile
constexpr int KW     = 128;          // k per wave (512 / 4 waves)
constexpr int BK     = 8;            // k per stage
constexpr int NSTAGE = KW / BK;      // 16

__global__ __launch_bounds__(256) void tropical_gemm(
    const float* __restrict__ X, const float* __restrict__ W,
    float* __restrict__ out) {
    __shared__ float lds[8192];   // 32 KB: main loop 4x1536, merge 2x4096 overlay

    const int tid  = threadIdx.x;
    const int w    = tid >> 6;     // wave 0..3
    const int lane = tid & 63;
    const int im   = lane >> 3;    // micro-row block 0..7 (x dir, 8 rows)
    const int in_  = lane & 7;     // micro-col block 0..7 (w dir, 4 cols)
    const int b0   = blockIdx.y * TM;
    const int o0   = blockIdx.x * TN;
    const int xoff = im * 8;
    const int woff = in_ * 4;
    const int wrow = lane >> 1;            // W staging: 2 lanes per row
    const int wk4  = (lane & 1) * 4;       // which k-half of the row's 8

    const float* Xp = X + (size_t)(b0 + lane) * IN_DIM + w * KW;
    const float* Wp = W + (size_t)(o0 + wrow) * IN_DIM + w * KW + wk4;

    float* wbase = &lds[w * 1536];  // wave-private: X[8][64] + W[8][32], x2 buf

    float mn[8][4], mx[8][4];
#pragma unroll
    for (int i = 0; i < 8; ++i)
#pragma unroll
        for (int j = 0; j < 4; ++j) { mn[i][j] = INFINITY; mx[i][j] = -INFINITY; }

    // stage one 8k chunk: X k-major [k][64], W k-major [k][32]
#define STAGE(bufsel)                                                         \
    do {                                                                      \
        float* d_ = wbase + (bufsel) * 768;                                   \
        _Pragma("unroll")                                                     \
        for (int j_ = 0; j_ < 4; ++j_) {                                      \
            d_[j_ * 64 + lane]       = xa[j_];                                \
            d_[(4 + j_) * 64 + lane] = xb[j_];                                \
            d_[512 + (wk4 + j_) * 32 + wrow] = wv[j_];                        \
        }                                                                     \
    } while (0)

    // load one k-pair's fragments (X: 8 floats x 2k, W: 4 floats x 2k)
#define LOADQ(P, kp)                                                          \
    do {                                                                      \
        P##x0  = *(const f4*)(sXf + (2 * (kp)) * 64 + xoff);                  \
        P##x0b = *(const f4*)(sXf + (2 * (kp)) * 64 + xoff + 4);              \
        P##x1  = *(const f4*)(sXf + (2 * (kp) + 1) * 64 + xoff);              \
        P##x1b = *(const f4*)(sXf + (2 * (kp) + 1) * 64 + xoff + 4);          \
        P##w0  = *(const f4*)(sWf + (2 * (kp)) * 32 + woff);                  \
        P##w1  = *(const f4*)(sWf + (2 * (kp) + 1) * 32 + woff);              \
    } while (0)

    // 32 (a,b) pairs over 2 k's: 2 v_add + v_min3 + v_max3 each
#define COMPUTE(P)                                                            \
    do {                                                                      \
        _Pragma("unroll")                                                     \
        for (int a_ = 0; a_ < 8; ++a_) {                                      \
            const float x0_ = (a_ < 4) ? P##x0[a_] : P##x0b[a_ - 4];          \
            const float x1_ = (a_ < 4) ? P##x1[a_] : P##x1b[a_ - 4];          \
            _Pragma("unroll")                                                 \
            for (int b_ = 0; b_ < 4; ++b_) {                                  \
                float s0_ = x0_ + P##w0[b_];                                  \
                float s1_ = x1_ + P##w1[b_];                                  \
                asm("v_min3_f32 %0, %1, %2, %0"                               \
                    : "+v"(mn[a_][b_]) : "v"(s0_), "v"(s1_));                 \
                asm("v_max3_f32 %0, %1, %2, %0"                               \
                    : "+v"(mx[a_][b_]) : "v"(s0_), "v"(s1_));                 \
            }                                                                 \
        }                                                                     \
    } while (0)

    // ---- prologue ----
    f4 xa = *(const f4*)(Xp);
    f4 xb = *(const f4*)(Xp + 4);
    f4 wv = *(const f4*)(Wp);
    STAGE(0);

#pragma unroll 1
    for (int s = 0; s < NSTAGE; ++s) {
        if (s + 1 < NSTAGE) {  // prefetch next chunk's globals
            xa = *(const f4*)(Xp + (s + 1) * BK);
            xb = *(const f4*)(Xp + (s + 1) * BK + 4);
            wv = *(const f4*)(Wp + (s + 1) * BK);
        }

        const float* sXf = wbase + (s & 1) * 768;
        const float* sWf = sXf + 512;

        f4 Ax0, Ax0b, Ax1, Ax1b, Aw0, Aw1;
        f4 Bx0, Bx0b, Bx1, Bx1b, Bw0, Bw1;

        LOADQ(A, 0);
        LOADQ(B, 1);
        COMPUTE(A);            // kp0 (B=kp1 in flight)
        LOADQ(A, 2);
        COMPUTE(B);            // kp1 (A=kp2 in flight)
        LOADQ(B, 3);
        COMPUTE(A);            // kp2 (B=kp3 in flight)
        COMPUTE(B);            // kp3

        if (s + 1 < NSTAGE) STAGE((s + 1) & 1);
    }
#undef STAGE
#undef LOADQ
#undef COMPUTE

    // ---- merge 4 wave partials: 2-round LDS tree ----
    // state/lane = 16 quads: q=r -> mn[r][0..3], q=8+r -> mx[r][0..3]
#define DUMP_STATE(slotbase)                                                  \
    do {                                                                      \
        float* p_ = (slotbase) + lane * 4;                                    \
        _Pragma("unroll")                                                     \
        for (int r_ = 0; r_ < 8; ++r_) {                                      \
            *(float4*)(p_ + r_ * 256) =                                       \
                make_float4(mn[r_][0], mn[r_][1], mn[r_][2], mn[r_][3]);      \
            *(float4*)(p_ + (8 + r_) * 256) =                                 \
                make_float4(mx[r_][0], mx[r_][1], mx[r_][2], mx[r_][3]);      \
        }                                                                     \
    } while (0)

#define MERGE_STATE(slotbase)                                                 \
    do {                                                                      \
        const float* p_ = (slotbase) + lane * 4;                              \
        _Pragma("unroll")                                                     \
        for (int r_ = 0; r_ < 8; ++r_) {                                      \
            float4 vn_ = *(const float4*)(p_ + r_ * 256);                     \
            float4 vx_ = *(const float4*)(p_ + (8 + r_) * 256);               \
            mn[r_][0] = fminf(mn[r_][0], vn_.x);                              \
            mn[r_][1] = fminf(mn[r_][1], vn_.y);                              \
            mn[r_][2] = fminf(mn[r_][2], vn_.z);                              \
            mn[r_][3] = fminf(mn[r_][3], vn_.w);                              \
            mx[r_][0] = fmaxf(mx[r_][0], vx_.x);                              \
            mx[r_][1] = fmaxf(mx[r_][1], vx_.y);                              \
            mx[r_][2] = fmaxf(mx[r_][2], vx_.z);                              \
            mx[r_][3] = fmaxf(mx[r_][3], vx_.w);                              \
        }                                                                     \
    } while (0)

    float* slotA = lds;           // 4096 floats
    float* slotB = lds + 4096;

    __syncthreads();
    if (w == 2) DUMP_STATE(slotA);
    if (w == 3) DUMP_STATE(slotB);
    __syncthreads();
    if (w == 0) MERGE_STATE(slotA);   // w0 <- {w0,w2}
    if (w == 1) MERGE_STATE(slotB);   // w1 <- {w1,w3}
    __syncthreads();
    if (w == 1) DUMP_STATE(slotA);
    __syncthreads();
    if (w == 0) {
        MERGE_STATE(slotA);           // w0 <- all
        float* op = out + (size_t)(b0 + im * 8) * O_DIM + o0 + in_ * 4;
#pragma unroll
        for (int r = 0; r < 8; ++r)
            *(float4*)(op + (size_t)r * O_DIM) =
                make_float4(mn[r][0] + mx[r][0], mn[r][1] + mx[r][1],
                            mn[r][2] + mx[r][2], mn[r][3] + mx[r][3]);
    }
#undef DUMP_STATE
#undef MERGE_STATE
}

extern "C" void kernel_launch(void* const* d_in, const int* in_sizes, int n_in,
                              void* d_out, int out_size, void* d_ws, size_t ws_size,
                              hipStream_t stream) {
    (void)in_sizes; (void)n_in; (void)d_ws; (void)ws_size; (void)out_size;
    const float* X = (const float*)d_in[0];
    const float* W = (const float*)d_in[1];
    float* out     = (float*)d_out;

    dim3 grid(O_DIM / TN, B_DIM / TM);  // (32, 16) = 512 blocks = 2/CU
    tropical_gemm<<<grid, dim3(256), 0, stream>>>(X, W, out);
}